// Round 13
// baseline (217.735 us; speedup 1.0000x reference)
//
#include <hip/hip_runtime.h>

#define SEQ     2048
#define DMODEL  1024
#define NHEADS  16
#define DKH     64
#define BATCH   4

typedef __bf16 bf16x8 __attribute__((ext_vector_type(8)));
typedef float  f32x4  __attribute__((ext_vector_type(4)));

static __device__ __forceinline__ unsigned short f2bf(float x) {
  unsigned int u = __float_as_uint(x);
  u += 0x7fffu + ((u >> 16) & 1u);
  return (unsigned short)(u >> 16);
}
static __device__ __forceinline__ float bf2f(unsigned short b) {
  return __uint_as_float(((unsigned int)b) << 16);
}
static __device__ __forceinline__ void gload_lds16(const void* g, void* lds) {
  __builtin_amdgcn_global_load_lds((const __attribute__((address_space(1))) void*)g,
                                   (__attribute__((address_space(3))) void*)lds,
                                   16, 0, 0);
}
static __device__ __forceinline__ f32x4 mfma16(bf16x8 a, bf16x8 b, f32x4 c) {
  return __builtin_amdgcn_mfma_f32_16x16x32_bf16(a, b, c, 0, 0, 0);
}

// ---------------- fp32 -> bf16 cast ----------------
__global__ void cast_kernel(const float* __restrict__ src,
                            unsigned short* __restrict__ dst, int n4) {
  int i = blockIdx.x * 256 + threadIdx.x;
  if (i >= n4) return;
  float4 v = ((const float4*)src)[i];
  ushort4 o;
  o.x = f2bf(v.x); o.y = f2bf(v.y); o.z = f2bf(v.z); o.w = f2bf(v.w);
  ((ushort4*)dst)[i] = o;
}

// 4 weight matrices in one launch (blockIdx.y selects)
__global__ void cast4_kernel(const float* __restrict__ s0, const float* __restrict__ s1,
                             const float* __restrict__ s2, const float* __restrict__ s3,
                             unsigned short* __restrict__ d0, unsigned short* __restrict__ d1,
                             unsigned short* __restrict__ d2, unsigned short* __restrict__ d3,
                             int n4) {
  int i = blockIdx.x * 256 + threadIdx.x;
  if (i >= n4) return;
  const float* s = (blockIdx.y == 0) ? s0 : (blockIdx.y == 1) ? s1 : (blockIdx.y == 2) ? s2 : s3;
  unsigned short* d = (blockIdx.y == 0) ? d0 : (blockIdx.y == 1) ? d1 : (blockIdx.y == 2) ? d2 : d3;
  float4 v = ((const float4*)s)[i];
  ushort4 o;
  o.x = f2bf(v.x); o.y = f2bf(v.y); o.z = f2bf(v.z); o.w = f2bf(v.w);
  ((ushort4*)d)[i] = o;
}

// ---------------- QKV GEMM: 128x256 tile, m201-cadence phase pipeline --------
// 4 waves (1M x 4N), per-wave 128x64 (acc[8][4]). BK=32, 2 phases per K-tile,
// 64 phases total. Per phase: {ds_reads, stage-gload issues} -> s_barrier ->
// lgkmcnt(0) -> setprio(1) 16xMFMA setprio(0) -> vmcnt(6) -> s_barrier.
// LDS 48 KiB (2-slot dbuf, sub-tile granularity): phase p+1's gloads target
// exactly the regions all waves finished reading in phase p (post-MFMA
// barrier = read-complete proof). vmcnt ledger: prologue 6+5 -> vmcnt(5);
// steady vmcnt(6); tail (t>=30) vmcnt(0). Grid 768 = 64m x 12zn (tail-free).
// RoPE fused into Q/K epilogue (Q scaled by log2e/8); V (z==2) -> V^T.
__global__ __launch_bounds__(256, 2)
void qkv_gemm(const unsigned short* __restrict__ A,
              const unsigned short* __restrict__ W0,
              const unsigned short* __restrict__ W1,
              const unsigned short* __restrict__ W2,
              unsigned short* __restrict__ O0,
              unsigned short* __restrict__ O1,
              unsigned short* __restrict__ O2)
{
  __shared__ unsigned short sA[2][128*32];   // 2 x 8 KiB
  __shared__ unsigned short sB[2][256*32];   // 2 x 16 KiB  (48 KiB total)
  const int tid = threadIdx.x;
  const int lane = tid & 63, w = tid >> 6;   // 4 waves, wave w owns n-cols w*64..
  const int li = lane & 15, lg = lane >> 4;

  // XCD swizzle over 768 blocks (96/XCD); n-fastest -> A-panel L2 reuse
  const int lgid = (blockIdx.x & 7) * 96 + (blockIdx.x >> 3);
  const int nt_i = lgid % 12;                // 12 n-tiles across the 3 weights
  const int m0 = (lgid / 12) * 128;
  const int z  = nt_i >> 2;
  const int n0 = (nt_i & 3) * 256;           // within the z-matrix
  const unsigned short* Bw = (z == 0) ? W0 : ((z == 1) ? W1 : W2);

  const f32x4 fz = {0.f, 0.f, 0.f, 0.f};
  f32x4 acc[8][4];
  #pragma unroll
  for (int a = 0; a < 8; ++a)
    #pragma unroll
    for (int b = 0; b < 4; ++b)
      acc[a][b] = fz;

  // stage A half (part 0: rows 0-63, part 1: rows 64-127): 1 gload/thread
  auto STG_A = [&](int buf, int t, int part) {
    int c = part*4 + w;                      // chunk 0..7
    int off16 = c*64 + lane;                 // 16B-slot 0..511
    int r = off16 >> 2, p = off16 & 3;       // row 0..127
    int s = p ^ ((r >> 1) & 3);              // proven conflict-free swizzle
    gload_lds16(A + (size_t)(m0 + r)*DMODEL + t*32 + s*8, (char*)sA[buf] + c*1024);
  };
  // stage full B tile (256 rows): 4 gloads/thread
  auto STG_B = [&](int buf, int t) {
    #pragma unroll
    for (int j = 0; j < 4; ++j) {
      int c = j*4 + w;                       // chunk 0..15
      int off16 = c*64 + lane;               // 0..1023
      int r = off16 >> 2, p = off16 & 3;     // row 0..255
      int s = p ^ ((r >> 1) & 3);
      gload_lds16(Bw + (size_t)(n0 + r)*DMODEL + t*32 + s*8, (char*)sB[buf] + c*1024);
    }
  };
  auto RD_A = [&](bf16x8* dst, int cur, int half) {
    #pragma unroll
    for (int i = 0; i < 4; ++i) {
      int rr = half*64 + i*16 + li;          // A row 0..127
      int sp = lg ^ ((rr >> 1) & 3);
      dst[i] = *(const bf16x8*)((const char*)sA[cur] + rr*64 + sp*16);
    }
  };
  auto RD_B = [&](bf16x8* dst, int cur) {
    #pragma unroll
    for (int i = 0; i < 4; ++i) {
      int rr = w*64 + i*16 + li;             // B row 0..255 (per-wave panel)
      int sp = lg ^ ((rr >> 1) & 3);
      dst[i] = *(const bf16x8*)((const char*)sB[cur] + rr*64 + sp*16);
    }
  };

  const int NT = DMODEL / 32;   // 32 K-tiles
  // prologue: t0 complete (6 loads), then t1 part0+B (5 loads)
  STG_A(0, 0, 0); STG_B(0, 0); STG_A(0, 0, 1);
  STG_A(1, 1, 0); STG_B(1, 1);
  asm volatile("s_waitcnt vmcnt(5)" ::: "memory");   // t0's 6 landed
  __builtin_amdgcn_s_barrier();
  __builtin_amdgcn_sched_barrier(0);

  for (int t = 0; t < NT; ++t) {
    const int cur = t & 1;
    // ---------------- phase 0: A rows 0-63 x B -> acc[0..3] ----------------
    bf16x8 a0[4], b0[4];
    RD_A(a0, cur, 0);
    RD_B(b0, cur);
    if (t + 1 < NT) STG_A(cur ^ 1, t + 1, 1);        // (t+1)'s A-part1 (1 load)
    __builtin_amdgcn_sched_barrier(0);
    __builtin_amdgcn_s_barrier();
    asm volatile("s_waitcnt lgkmcnt(0)" ::: "memory");
    __builtin_amdgcn_sched_barrier(0);
    __builtin_amdgcn_s_setprio(1);
    #pragma unroll
    for (int i = 0; i < 4; ++i)
      #pragma unroll
      for (int j = 0; j < 4; ++j)
        acc[i][j] = mfma16(a0[i], b0[j], acc[i][j]);
    __builtin_amdgcn_s_setprio(0);
    __builtin_amdgcn_sched_barrier(0);
    if (t >= NT - 2) asm volatile("s_waitcnt vmcnt(0)" ::: "memory");
    else             asm volatile("s_waitcnt vmcnt(6)" ::: "memory");
    __builtin_amdgcn_s_barrier();

    // ---------------- phase 1: A rows 64-127 x B -> acc[4..7] --------------
    bf16x8 a1[4];
    RD_A(a1, cur, 1);
    if (t + 2 < NT) {                                // (t+2)'s A-part0 + B (5)
      STG_A(cur, t + 2, 0);
      STG_B(cur, t + 2);
    }
    __builtin_amdgcn_sched_barrier(0);
    __builtin_amdgcn_s_barrier();
    asm volatile("s_waitcnt lgkmcnt(0)" ::: "memory");
    __builtin_amdgcn_sched_barrier(0);
    __builtin_amdgcn_s_setprio(1);
    #pragma unroll
    for (int i = 0; i < 4; ++i)
      #pragma unroll
      for (int j = 0; j < 4; ++j)
        acc[4 + i][j] = mfma16(a1[i], b0[j], acc[4 + i][j]);
    __builtin_amdgcn_s_setprio(0);
    __builtin_amdgcn_sched_barrier(0);
    if (t >= NT - 2) asm volatile("s_waitcnt vmcnt(0)" ::: "memory");
    else             asm volatile("s_waitcnt vmcnt(6)" ::: "memory");
    __builtin_amdgcn_s_barrier();
  }

  unsigned short* Odst = (z == 0) ? O0 : ((z == 1) ? O1 : O2);

  // invfreq per ni (dk = (w*64 + ni*16 + li) & 63 = ni*16 + li; i = dk>>1)
  float invf[4];
  #pragma unroll
  for (int ni = 0; ni < 4; ++ni) {
    int i_of = (ni*16 + li) >> 1;
    invf[ni] = exp2f(-0.41524101186092029f * (float)i_of);
  }

  #pragma unroll
  for (int mi = 0; mi < 8; ++mi) {
    #pragma unroll
    for (int ni = 0; ni < 4; ++ni) {
      #pragma unroll
      for (int r = 0; r < 4; ++r) {
        int m = m0 + mi*16 + lg*4 + r;            // D row = (lane>>4)*4 + reg
        int n = n0 + w*64 + ni*16 + li;           // col within z-matrix
        float v = acc[mi][ni][r];
        int b = m >> 11, sq = m & (SEQ-1), hh = n >> 6, dk = n & 63;
        float prt = __shfl_xor(v, 1);             // RoPE pair (adjacent lanes)
        if (z == 2) {
          Odst[(((size_t)b*NHEADS + hh)*DKH + dk)*SEQ + sq] = f2bf(v);   // V^T
        } else {
          float ang = (float)sq * invf[ni];
          float sn, cs;
          __sincosf(ang, &sn, &cs);
          float out = (li & 1) ? (sn*prt + cs*v) : (cs*v - sn*prt);
          if (z == 0) out *= 0.18033688011112043f;   // (1/8) * log2(e)
          Odst[(((size_t)b*NHEADS + hh)*SEQ + sq)*DKH + dk] = f2bf(out);
        }
      }
    }
  }
}

// ---------------- out-proj GEMM (frozen round-8 structure) ----------------
__global__ __launch_bounds__(256)
void gemm_out(const unsigned short* __restrict__ A,
              const unsigned short* __restrict__ W0,
              float* __restrict__ Of)
{
  __shared__ unsigned short sA[2][128*64];
  __shared__ unsigned short sB[2][128*64];
  const int tid = threadIdx.x;
  const int lane = tid & 63, w = tid >> 6;
  const int wm = w >> 1, wn = w & 1;
  const int li = lane & 15, lg = lane >> 4;

  const int lgid = (blockIdx.x & 7) * 64 + (blockIdx.x >> 3);
  const int n0 = (lgid & 7) * 128;
  const int m0 = ((lgid >> 3) & 63) * 128;
  const unsigned short* Bw = W0;

  const f32x4 fz = {0.f, 0.f, 0.f, 0.f};
  f32x4 acc[4][4];
  #pragma unroll
  for (int a = 0; a < 4; ++a)
    #pragma unroll
    for (int b = 0; b < 4; ++b)
      acc[a][b] = fz;

  auto STAGE = [&](int buf, int t) {
    const int k0 = t * 64;
    #pragma unroll
    for (int it = 0; it < 4; ++it) {
      int c = it*4 + w;
      int off16 = c*64 + lane;
      int r = off16 >> 3, p = off16 & 7;
      int s = p ^ (r & 7);
      gload_lds16(A  + (size_t)(m0 + r)*DMODEL + k0 + s*8, (char*)sA[buf] + c*1024);
      gload_lds16(Bw + (size_t)(n0 + r)*DMODEL + k0 + s*8, (char*)sB[buf] + c*1024);
    }
  };

  const int NT = DMODEL / 64;
  STAGE(0, 0);
  STAGE(1, 1);

  for (int t = 0; t < NT; ++t) {
    const int cur = t & 1;
    if (t == NT - 1) asm volatile("s_waitcnt vmcnt(0)" ::: "memory");
    else             asm volatile("s_waitcnt vmcnt(8)" ::: "memory");
    __builtin_amdgcn_s_barrier();
    __builtin_amdgcn_sched_barrier(0);

    #pragma unroll
    for (int kf = 0; kf < 2; ++kf) {
      bf16x8 af[4], bfr[4];
      #pragma unroll
      for (int mi = 0; mi < 4; ++mi) {
        int rr = wm*64 + mi*16 + li;
        int sp = (kf*4 + lg) ^ (rr & 7);
        af[mi] = *(const bf16x8*)(sA[cur] + rr*64 + sp*8);
      }
      #pragma unroll
      for (int ni = 0; ni < 4; ++ni) {
        int rr = wn*64 + ni*16 + li;
        int sp = (kf*4 + lg) ^ (rr & 7);
        bfr[ni] = *(const bf16x8*)(sB[cur] + rr*64 + sp*8);
      }
      __builtin_amdgcn_s_setprio(1);
      #pragma unroll
      for (int mi = 0; mi < 4; ++mi)
        #pragma unroll
        for (int ni = 0; ni < 4; ++ni)
          acc[mi][ni] = mfma16(af[mi], bfr[ni], acc[mi][ni]);
      __builtin_amdgcn_s_setprio(0);
    }

    __builtin_amdgcn_sched_barrier(0);
    __builtin_amdgcn_s_barrier();
    __builtin_amdgcn_sched_barrier(0);
    if (t + 2 < NT) STAGE(cur, t + 2);
  }

  #pragma unroll
  for (int mi = 0; mi < 4; ++mi)
    #pragma unroll
    for (int ni = 0; ni < 4; ++ni)
      #pragma unroll
      for (int r = 0; r < 4; ++r) {
        int m = m0 + wm*64 + mi*16 + lg*4 + r;
        int n = n0 + wn*64 + ni*16 + li;
        Of[(size_t)m*DMODEL + n] = acc[mi][ni][r];
      }
}

// ---------------- causal flash attention (frozen round-11) ----------------
__global__ __launch_bounds__(512)
void attn_kernel(const unsigned short* __restrict__ Qg,
                 const unsigned short* __restrict__ Kg,
                 const unsigned short* __restrict__ Vtg,
                 unsigned short* __restrict__ Og)
{
  const int lgid = (blockIdx.x & 7) * 64 + (blockIdx.x >> 3);
  const int px = lgid & 7;
  const int bh = lgid >> 3;
  const int tid = threadIdx.x;
  const int lane = tid & 63, w = tid >> 6;
  const int li = lane & 15, lg = lane >> 4;
  const float THRL2 = 11.0f;

  __shared__ unsigned short sK[2][64*64];
  __shared__ unsigned short sV[2][64*64];
  __shared__ unsigned short sP[8][16*72];
  unsigned short* sPw = sP[w];

  const size_t bhBase = (size_t)bh * SEQ * DKH;

  bf16x8 onesf;
  {
    __bf16 ob = (__bf16)1.0f;
    #pragma unroll
    for (int j = 0; j < 8; ++j) onesf[j] = ob;
  }
  const f32x4 fz = {0.f, 0.f, 0.f, 0.f};

  auto STAGE = [&](int buf, int t) {
    const int kv0 = t * 64;
    int off16 = w*64 + lane;
    int r = off16 >> 3, p = off16 & 7;
    int s = p ^ (r & 7);
    gload_lds16(Kg  + bhBase + (size_t)(kv0 + r)*DKH + s*8, (char*)sK[buf] + w*1024);
    gload_lds16(Vtg + bhBase + (size_t)r*SEQ + kv0 + s*8,   (char*)sV[buf] + w*1024);
  };

  #pragma unroll 1
  for (int pass = 0; pass < 2; ++pass) {
    const int qt = pass ? (15 - px) : px;
    const int q0 = qt * 128;
    const int myrow0 = q0 + w*16;

    bf16x8 qf[2];
    {
      const unsigned short* qp = Qg + bhBase + (size_t)(myrow0 + li)*DKH + lg*8;
      qf[0] = *(const bf16x8*)qp;
      qf[1] = *(const bf16x8*)(qp + 32);
    }

    f32x4 acc_o[4], ls4;
    float m_r[4];
    #pragma unroll
    for (int nt = 0; nt < 4; ++nt) acc_o[nt] = fz;
    ls4 = fz;
    #pragma unroll
    for (int kr = 0; kr < 4; ++kr) m_r[kr] = -1e30f;

    const int nt_stage = 2*qt + 2;
    const int last_t  = 2*qt + (w >= 4 ? 1 : 0);

    STAGE(0, 0);
    STAGE(1, 1);

    for (int t = 0; t < nt_stage; ++t) {
      const int cur = t & 1;
      if (t == nt_stage - 1) asm volatile("s_waitcnt vmcnt(0)" ::: "memory");
      else                   asm volatile("s_waitcnt vmcnt(2)" ::: "memory");
      __builtin_amdgcn_s_barrier();
      __builtin_amdgcn_sched_barrier(0);

      if (t <= last_t) {
        const int kv0 = t * 64;
        f32x4 sc[4];
        #pragma unroll
        for (int nt = 0; nt < 4; ++nt) sc[nt] = fz;
        __builtin_amdgcn_s_setprio(1);
        #pragma unroll
        for (int kf = 0; kf < 2; ++kf) {
          #pragma unroll
          for (int nt = 0; nt < 4; ++nt) {
            int row = nt*16 + li;
            int sp = (kf*4 + lg) ^ (row & 7);
            bf16x8 kb = *(const bf16x8*)(sK[cur] + row*64 + sp*8);
            sc[nt] = mfma16(qf[kf], kb, sc[nt]);
          }
        }
        __builtin_amdgcn_s_setprio(0);

        if (t == last_t) {
          #pragma unroll
          for (int nt = 0; nt < 4; ++nt)
            #pragma unroll
            for (int kr = 0; kr < 4; ++kr) {
              int col = kv0 + nt*16 + li;
              int row = myrow0 + lg*4 + kr;
              if (col > row) sc[nt][kr] = -1e30f;
            }
        }

        float mx[4], grow = 0.f;
        #pragma unroll
        for (int kr = 0; kr < 4; ++kr) {
          float m2 = fmaxf(fmaxf(sc[0][kr], sc[1][kr]), fmaxf(sc[2][kr], sc[3][kr]));
          m2 = fmaxf(m2, __shfl_xor(m2, 1));
          m2 = fmaxf(m2, __shfl_xor(m2, 2));
          m2 = fmaxf(m2, __shfl_xor(m2, 4));
          m2 = fmaxf(m2, __shfl_xor(m2, 8));
          mx[kr] = m2;
          grow = fmaxf(grow, m2 - m_r[kr]);
        }
        if (grow > THRL2) {
          #pragma unroll
          for (int kr = 0; kr < 4; ++kr) {
            float mn = fmaxf(m_r[kr], mx[kr]);
            float scl = __builtin_amdgcn_exp2f(m_r[kr] - mn);
            m_r[kr] = mn;
            #pragma unroll
            for (int nt = 0; nt < 4; ++nt) acc_o[nt][kr] *= scl;
            ls4[kr] *= scl;
          }
        }
        #pragma unroll
        for (int nt = 0; nt < 4; ++nt)
          #pragma unroll
          for (int kr = 0; kr < 4; ++kr)
            sc[nt][kr] = __builtin_amdgcn_exp2f(sc[nt][kr] - m_r[kr]);

        #pragma unroll
        for (int nt = 0; nt < 4; ++nt)
          #pragma unroll
          for (int kr = 0; kr < 4; ++kr)
            sPw[(lg*4 + kr)*72 + nt*16 + li] = f2bf(sc[nt][kr]);

        bf16x8 pa[2];
        #pragma unroll
        for (int kf = 0; kf < 2; ++kf)
          pa[kf] = *(const bf16x8*)(sPw + li*72 + kf*32 + lg*8);

        __builtin_amdgcn_s_setprio(1);
        ls4 = mfma16(pa[0], onesf, ls4);
        ls4 = mfma16(pa[1], onesf, ls4);
        #pragma unroll
        for (int kf = 0; kf < 2; ++kf)
          #pragma unroll
          for (int nt = 0; nt < 4; ++nt) {
            int rr = nt*16 + li;
            int sp = (kf*4 + lg) ^ (rr & 7);
            bf16x8 vb = *(const bf16x8*)(sV[cur] + rr*64 + sp*8);
            acc_o[nt] = mfma16(pa[kf], vb, acc_o[nt]);
          }
        __builtin_amdgcn_s_setprio(0);
      }

      __builtin_amdgcn_sched_barrier(0);
      __builtin_amdgcn_s_barrier();
      __builtin_amdgcn_sched_barrier(0);
      if (t + 2 < nt_stage) STAGE(cur, t + 2);
    }

    const int b = bh >> 4, hh = bh & 15;
    #pragma unroll
    for (int kr = 0; kr < 4; ++kr) {
      float inv = __builtin_amdgcn_rcpf(ls4[kr]);
      int srow = myrow0 + lg*4 + kr;
      size_t orow = ((size_t)b*SEQ + srow)*DMODEL + (size_t)hh*DKH;
      #pragma unroll
      for (int nt = 0; nt < 4; ++nt)
        Og[orow + nt*16 + li] = f2bf(acc_o[nt][kr] * inv);
    }
  }
}

extern "C" void kernel_launch(void* const* d_in, const int* in_sizes, int n_in,
                              void* d_out, int out_size, void* d_ws, size_t ws_size,
                              hipStream_t stream)
{
  (void)in_sizes; (void)n_in; (void)out_size; (void)ws_size;
  const float* X  = (const float*)d_in[0];
  const float* Wq = (const float*)d_in[1];
  const float* Wk = (const float*)d_in[2];
  const float* Wv = (const float*)d_in[3];
  const float* Wo = (const float*)d_in[4];

  // d_ws budget: 40 MiB. Q/K bf16 scratch (32 MiB) lives inside d_out (33.5 MiB),
  // dead until the final out-projection overwrites it (stream-ordered).
  char* ws = (char*)d_ws;
  const size_t SZ_X = (size_t)8192 * 1024 * 2;   // 16 MiB (bf16)
  const size_t SZ_W = (size_t)1024 * 1024 * 2;   // 2 MiB  (bf16)
  unsigned short* Xb  = (unsigned short*)(ws);
  unsigned short* Wqb = (unsigned short*)(ws + SZ_X);
  unsigned short* Wkb = (unsigned short*)(ws + SZ_X + 1*SZ_W);
  unsigned short* Wvb = (unsigned short*)(ws + SZ_X + 2*SZ_W);
  unsigned short* Wob = (unsigned short*)(ws + SZ_X + 3*SZ_W);
  unsigned short* Vtb = (unsigned short*)(ws + SZ_X + 4*SZ_W);   // V^T, ..40 MiB
  unsigned short* Qb  = (unsigned short*)d_out;                  // 16 MiB scratch
  unsigned short* Kb  = Qb + (size_t)8192 * 1024;                // 16 MiB scratch
  unsigned short* Ob  = Xb;   // X dead after QKV projection

  cast_kernel<<<8192, 256, 0, stream>>>(X, Xb, 8388608/4);
  cast4_kernel<<<dim3(1024, 4), 256, 0, stream>>>(Wq, Wk, Wv, Wo,
                                                  Wqb, Wkb, Wvb, Wob, 1048576/4);

  qkv_gemm<<<768, 256, 0, stream>>>(Xb, Wqb, Wkb, Wvb, Qb, Kb, Vtb);
  attn_kernel<<<512, 512, 0, stream>>>(Qb, Kb, Vtb, Ob);
  gemm_out<<<512, 256, 0, stream>>>(Ob, Wob, (float*)d_out);
}

// Round 14
// 192.816 us; speedup vs baseline: 1.1292x; 1.1292x over previous
//
#include <hip/hip_runtime.h>

#define SEQ     2048
#define DMODEL  1024
#define NHEADS  16
#define DKH     64
#define BATCH   4

typedef __bf16 bf16x8 __attribute__((ext_vector_type(8)));
typedef float  f32x4  __attribute__((ext_vector_type(4)));

static __device__ __forceinline__ unsigned short f2bf(float x) {
  unsigned int u = __float_as_uint(x);
  u += 0x7fffu + ((u >> 16) & 1u);
  return (unsigned short)(u >> 16);
}
static __device__ __forceinline__ float bf2f(unsigned short b) {
  return __uint_as_float(((unsigned int)b) << 16);
}
static __device__ __forceinline__ void gload_lds16(const void* g, void* lds) {
  __builtin_amdgcn_global_load_lds((const __attribute__((address_space(1))) void*)g,
                                   (__attribute__((address_space(3))) void*)lds,
                                   16, 0, 0);
}
static __device__ __forceinline__ f32x4 mfma16(bf16x8 a, bf16x8 b, f32x4 c) {
  return __builtin_amdgcn_mfma_f32_16x16x32_bf16(a, b, c, 0, 0, 0);
}

// ---------------- fp32 -> bf16 cast ----------------
__global__ void cast_kernel(const float* __restrict__ src,
                            unsigned short* __restrict__ dst, int n4) {
  int i = blockIdx.x * 256 + threadIdx.x;
  if (i >= n4) return;
  float4 v = ((const float4*)src)[i];
  ushort4 o;
  o.x = f2bf(v.x); o.y = f2bf(v.y); o.z = f2bf(v.z); o.w = f2bf(v.w);
  ((ushort4*)dst)[i] = o;
}

// 4 weight matrices in one launch (blockIdx.y selects)
__global__ void cast4_kernel(const float* __restrict__ s0, const float* __restrict__ s1,
                             const float* __restrict__ s2, const float* __restrict__ s3,
                             unsigned short* __restrict__ d0, unsigned short* __restrict__ d1,
                             unsigned short* __restrict__ d2, unsigned short* __restrict__ d3,
                             int n4) {
  int i = blockIdx.x * 256 + threadIdx.x;
  if (i >= n4) return;
  const float* s = (blockIdx.y == 0) ? s0 : (blockIdx.y == 1) ? s1 : (blockIdx.y == 2) ? s2 : s3;
  unsigned short* d = (blockIdx.y == 0) ? d0 : (blockIdx.y == 1) ? d1 : (blockIdx.y == 2) ? d2 : d3;
  float4 v = ((const float4*)s)[i];
  ushort4 o;
  o.x = f2bf(v.x); o.y = f2bf(v.y); o.z = f2bf(v.z); o.w = f2bf(v.w);
  ((ushort4*)d)[i] = o;
}

// ---------------- GEMM: C = A (8192x1024) * W^T, W is [out][in] ----------------
// PROVEN structure (best of 6 tilings tried): 128x128 tile, 4 waves, BK=64,
// double-buffered, counted vmcnt(8), raw barriers. EPI 0: RoPE fused into
// Q/K epilogue (Q scaled by log2e/8); V (z==2) -> V^T. EPI 1: fp32 out.
template<int EPI>
__global__ __launch_bounds__(256)
void gemm_bt(const unsigned short* __restrict__ A,
             const unsigned short* __restrict__ W0,
             const unsigned short* __restrict__ W1,
             const unsigned short* __restrict__ W2,
             unsigned short* __restrict__ O0,
             unsigned short* __restrict__ O1,
             unsigned short* __restrict__ O2,
             float* __restrict__ Of)
{
  __shared__ unsigned short sA[2][128*64];
  __shared__ unsigned short sB[2][128*64];
  const int tid = threadIdx.x;
  const int lane = tid & 63, w = tid >> 6;
  const int wm = w >> 1, wn = w & 1;
  const int li = lane & 15, lg = lane >> 4;

  const int NWG = (EPI == 0) ? 1536 : 512;
  const int CPX = NWG / 8;
  const int lgid = (blockIdx.x & 7) * CPX + (blockIdx.x >> 3);
  const int n0 = (lgid & 7) * 128;
  const int m0 = ((lgid >> 3) & 63) * 128;
  const int z  = (EPI == 0) ? (lgid >> 9) : 0;
  const unsigned short* Bw = (EPI == 0)
      ? ((z == 0) ? W0 : ((z == 1) ? W1 : W2)) : W0;

  const f32x4 fz = {0.f, 0.f, 0.f, 0.f};
  f32x4 acc[4][4];
  #pragma unroll
  for (int a = 0; a < 4; ++a)
    #pragma unroll
    for (int b = 0; b < 4; ++b)
      acc[a][b] = fz;

  auto STAGE = [&](int buf, int t) {
    const int k0 = t * 64;
    #pragma unroll
    for (int it = 0; it < 4; ++it) {
      int c = it*4 + w;
      int off16 = c*64 + lane;
      int r = off16 >> 3, p = off16 & 7;
      int s = p ^ (r & 7);
      gload_lds16(A  + (size_t)(m0 + r)*DMODEL + k0 + s*8, (char*)sA[buf] + c*1024);
      gload_lds16(Bw + (size_t)(n0 + r)*DMODEL + k0 + s*8, (char*)sB[buf] + c*1024);
    }
  };

  const int NT = DMODEL / 64;
  STAGE(0, 0);
  STAGE(1, 1);

  for (int t = 0; t < NT; ++t) {
    const int cur = t & 1;
    if (t == NT - 1) asm volatile("s_waitcnt vmcnt(0)" ::: "memory");
    else             asm volatile("s_waitcnt vmcnt(8)" ::: "memory");
    __builtin_amdgcn_s_barrier();
    __builtin_amdgcn_sched_barrier(0);

    #pragma unroll
    for (int kf = 0; kf < 2; ++kf) {
      bf16x8 af[4], bfr[4];
      #pragma unroll
      for (int mi = 0; mi < 4; ++mi) {
        int rr = wm*64 + mi*16 + li;
        int sp = (kf*4 + lg) ^ (rr & 7);
        af[mi] = *(const bf16x8*)(sA[cur] + rr*64 + sp*8);
      }
      #pragma unroll
      for (int ni = 0; ni < 4; ++ni) {
        int rr = wn*64 + ni*16 + li;
        int sp = (kf*4 + lg) ^ (rr & 7);
        bfr[ni] = *(const bf16x8*)(sB[cur] + rr*64 + sp*8);
      }
      __builtin_amdgcn_s_setprio(1);
      #pragma unroll
      for (int mi = 0; mi < 4; ++mi)
        #pragma unroll
        for (int ni = 0; ni < 4; ++ni)
          acc[mi][ni] = mfma16(af[mi], bfr[ni], acc[mi][ni]);
      __builtin_amdgcn_s_setprio(0);
    }

    __builtin_amdgcn_sched_barrier(0);
    __builtin_amdgcn_s_barrier();
    __builtin_amdgcn_sched_barrier(0);
    if (t + 2 < NT) STAGE(cur, t + 2);
  }

  unsigned short* Odst = O0;
  if (EPI == 0) Odst = (z == 0) ? O0 : ((z == 1) ? O1 : O2);

  float invf[4];
  if (EPI == 0) {
    #pragma unroll
    for (int ni = 0; ni < 4; ++ni) {
      int i_of = (ni*16 + li) >> 1;
      invf[ni] = exp2f(-0.41524101186092029f * (float)i_of);
    }
  }

  #pragma unroll
  for (int mi = 0; mi < 4; ++mi) {
    #pragma unroll
    for (int ni = 0; ni < 4; ++ni) {
      #pragma unroll
      for (int r = 0; r < 4; ++r) {
        int m = m0 + wm*64 + mi*16 + lg*4 + r;   // D row = (lane>>4)*4 + reg
        int n = n0 + wn*64 + ni*16 + li;         // D col = lane&15
        float v = acc[mi][ni][r];
        if (EPI == 0) {
          int b = m >> 11, sq = m & (SEQ-1), hh = n >> 6, dk = n & 63;
          float prt = __shfl_xor(v, 1);          // RoPE pair (adjacent lanes)
          if (z == 2) {
            Odst[(((size_t)b*NHEADS + hh)*DKH + dk)*SEQ + sq] = f2bf(v);   // V^T
          } else {
            float ang = (float)sq * invf[ni];
            float sn, cs;
            __sincosf(ang, &sn, &cs);
            float out = (li & 1) ? (sn*prt + cs*v) : (cs*v - sn*prt);
            if (z == 0) out *= 0.18033688011112043f;   // (1/8) * log2(e)
            Odst[(((size_t)b*NHEADS + hh)*SEQ + sq)*DKH + dk] = f2bf(out);
          }
        } else {
          Of[(size_t)m*DMODEL + n] = v;
        }
      }
    }
  }
}

// ---------------- causal flash attention ----------------
// 1-D grid 512 (XCD-swizzled): block = pair of 128-row q-tiles {px, 15-px}.
// 8 waves x 16 q-rows. V supplied V^T. exp2-domain softmax (raw v_exp_f32).
// K/V double-buffered with counted vmcnt + raw barriers (round-11 proven).
// NEW (T13 full recipe): per-lane max test; the 16-lane shuffle reduction
// tree AND the rescale run only when some lane exceeds m_r + THR (first
// tile always triggers; later tiles ~never on this data). P bounded by
// 2^THR = 2048 — safe in bf16/f32, normalized away in the epilogue.
__global__ __launch_bounds__(512)
void attn_kernel(const unsigned short* __restrict__ Qg,
                 const unsigned short* __restrict__ Kg,
                 const unsigned short* __restrict__ Vtg,
                 unsigned short* __restrict__ Og)
{
  const int lgid = (blockIdx.x & 7) * 64 + (blockIdx.x >> 3);
  const int px = lgid & 7;
  const int bh = lgid >> 3;
  const int tid = threadIdx.x;
  const int lane = tid & 63, w = tid >> 6;
  const int li = lane & 15, lg = lane >> 4;
  const float THRL2 = 11.0f;

  __shared__ unsigned short sK[2][64*64];
  __shared__ unsigned short sV[2][64*64];
  __shared__ unsigned short sP[8][16*72];
  unsigned short* sPw = sP[w];

  const size_t bhBase = (size_t)bh * SEQ * DKH;

  bf16x8 onesf;
  {
    __bf16 ob = (__bf16)1.0f;
    #pragma unroll
    for (int j = 0; j < 8; ++j) onesf[j] = ob;
  }
  const f32x4 fz = {0.f, 0.f, 0.f, 0.f};

  auto STAGE = [&](int buf, int t) {
    const int kv0 = t * 64;
    int off16 = w*64 + lane;
    int r = off16 >> 3, p = off16 & 7;
    int s = p ^ (r & 7);
    gload_lds16(Kg  + bhBase + (size_t)(kv0 + r)*DKH + s*8, (char*)sK[buf] + w*1024);
    gload_lds16(Vtg + bhBase + (size_t)r*SEQ + kv0 + s*8,   (char*)sV[buf] + w*1024);
  };

  #pragma unroll 1
  for (int pass = 0; pass < 2; ++pass) {
    const int qt = pass ? (15 - px) : px;
    const int q0 = qt * 128;
    const int myrow0 = q0 + w*16;

    bf16x8 qf[2];
    {
      const unsigned short* qp = Qg + bhBase + (size_t)(myrow0 + li)*DKH + lg*8;
      qf[0] = *(const bf16x8*)qp;
      qf[1] = *(const bf16x8*)(qp + 32);
    }

    f32x4 acc_o[4], ls4;
    float m_r[4];
    #pragma unroll
    for (int nt = 0; nt < 4; ++nt) acc_o[nt] = fz;
    ls4 = fz;
    #pragma unroll
    for (int kr = 0; kr < 4; ++kr) m_r[kr] = -1e30f;

    const int nt_stage = 2*qt + 2;
    const int last_t  = 2*qt + (w >= 4 ? 1 : 0);

    STAGE(0, 0);
    STAGE(1, 1);

    for (int t = 0; t < nt_stage; ++t) {
      const int cur = t & 1;
      if (t == nt_stage - 1) asm volatile("s_waitcnt vmcnt(0)" ::: "memory");
      else                   asm volatile("s_waitcnt vmcnt(2)" ::: "memory");
      __builtin_amdgcn_s_barrier();
      __builtin_amdgcn_sched_barrier(0);

      if (t <= last_t) {
        const int kv0 = t * 64;
        f32x4 sc[4];
        #pragma unroll
        for (int nt = 0; nt < 4; ++nt) sc[nt] = fz;
        __builtin_amdgcn_s_setprio(1);
        #pragma unroll
        for (int kf = 0; kf < 2; ++kf) {
          #pragma unroll
          for (int nt = 0; nt < 4; ++nt) {
            int row = nt*16 + li;
            int sp = (kf*4 + lg) ^ (row & 7);
            bf16x8 kb = *(const bf16x8*)(sK[cur] + row*64 + sp*8);
            sc[nt] = mfma16(qf[kf], kb, sc[nt]);
          }
        }
        __builtin_amdgcn_s_setprio(0);

        if (t == last_t) {
          #pragma unroll
          for (int nt = 0; nt < 4; ++nt)
            #pragma unroll
            for (int kr = 0; kr < 4; ++kr) {
              int col = kv0 + nt*16 + li;
              int row = myrow0 + lg*4 + kr;
              if (col > row) sc[nt][kr] = -1e30f;
            }
        }

        // T13 lazy max: per-lane max test; tree+rescale only when exceeded
        float pm[4];
        #pragma unroll
        for (int kr = 0; kr < 4; ++kr)
          pm[kr] = fmaxf(fmaxf(sc[0][kr], sc[1][kr]), fmaxf(sc[2][kr], sc[3][kr]));
        int need = (pm[0] > m_r[0] + THRL2) | (pm[1] > m_r[1] + THRL2) |
                   (pm[2] > m_r[2] + THRL2) | (pm[3] > m_r[3] + THRL2);
        if (__any(need)) {
          #pragma unroll
          for (int kr = 0; kr < 4; ++kr) {
            float m2 = pm[kr];
            m2 = fmaxf(m2, __shfl_xor(m2, 1));
            m2 = fmaxf(m2, __shfl_xor(m2, 2));
            m2 = fmaxf(m2, __shfl_xor(m2, 4));
            m2 = fmaxf(m2, __shfl_xor(m2, 8));
            float mn = fmaxf(m_r[kr], m2);
            float scl = __builtin_amdgcn_exp2f(m_r[kr] - mn);
            m_r[kr] = mn;
            #pragma unroll
            for (int nt = 0; nt < 4; ++nt) acc_o[nt][kr] *= scl;
            ls4[kr] *= scl;
          }
        }
        #pragma unroll
        for (int nt = 0; nt < 4; ++nt)
          #pragma unroll
          for (int kr = 0; kr < 4; ++kr)
            sc[nt][kr] = __builtin_amdgcn_exp2f(sc[nt][kr] - m_r[kr]);

        #pragma unroll
        for (int nt = 0; nt < 4; ++nt)
          #pragma unroll
          for (int kr = 0; kr < 4; ++kr)
            sPw[(lg*4 + kr)*72 + nt*16 + li] = f2bf(sc[nt][kr]);

        bf16x8 pa[2];
        #pragma unroll
        for (int kf = 0; kf < 2; ++kf)
          pa[kf] = *(const bf16x8*)(sPw + li*72 + kf*32 + lg*8);

        __builtin_amdgcn_s_setprio(1);
        ls4 = mfma16(pa[0], onesf, ls4);
        ls4 = mfma16(pa[1], onesf, ls4);
        #pragma unroll
        for (int kf = 0; kf < 2; ++kf)
          #pragma unroll
          for (int nt = 0; nt < 4; ++nt) {
            int rr = nt*16 + li;
            int sp = (kf*4 + lg) ^ (rr & 7);
            bf16x8 vb = *(const bf16x8*)(sV[cur] + rr*64 + sp*8);
            acc_o[nt] = mfma16(pa[kf], vb, acc_o[nt]);
          }
        __builtin_amdgcn_s_setprio(0);
      }

      __builtin_amdgcn_sched_barrier(0);
      __builtin_amdgcn_s_barrier();
      __builtin_amdgcn_sched_barrier(0);
      if (t + 2 < nt_stage) STAGE(cur, t + 2);
    }

    const int b = bh >> 4, hh = bh & 15;
    #pragma unroll
    for (int kr = 0; kr < 4; ++kr) {
      float inv = __builtin_amdgcn_rcpf(ls4[kr]);
      int srow = myrow0 + lg*4 + kr;
      size_t orow = ((size_t)b*SEQ + srow)*DMODEL + (size_t)hh*DKH;
      #pragma unroll
      for (int nt = 0; nt < 4; ++nt)
        Og[orow + nt*16 + li] = f2bf(acc_o[nt][kr] * inv);
    }
  }
}

extern "C" void kernel_launch(void* const* d_in, const int* in_sizes, int n_in,
                              void* d_out, int out_size, void* d_ws, size_t ws_size,
                              hipStream_t stream)
{
  (void)in_sizes; (void)n_in; (void)out_size; (void)ws_size;
  const float* X  = (const float*)d_in[0];
  const float* Wq = (const float*)d_in[1];
  const float* Wk = (const float*)d_in[2];
  const float* Wv = (const float*)d_in[3];
  const float* Wo = (const float*)d_in[4];

  // d_ws budget: 40 MiB. Q/K bf16 scratch (32 MiB) lives inside d_out (33.5 MiB),
  // dead until the final out-projection overwrites it (stream-ordered).
  char* ws = (char*)d_ws;
  const size_t SZ_X = (size_t)8192 * 1024 * 2;   // 16 MiB (bf16)
  const size_t SZ_W = (size_t)1024 * 1024 * 2;   // 2 MiB  (bf16)
  unsigned short* Xb  = (unsigned short*)(ws);
  unsigned short* Wqb = (unsigned short*)(ws + SZ_X);
  unsigned short* Wkb = (unsigned short*)(ws + SZ_X + 1*SZ_W);
  unsigned short* Wvb = (unsigned short*)(ws + SZ_X + 2*SZ_W);
  unsigned short* Wob = (unsigned short*)(ws + SZ_X + 3*SZ_W);
  unsigned short* Vtb = (unsigned short*)(ws + SZ_X + 4*SZ_W);   // V^T, ..40 MiB
  unsigned short* Qb  = (unsigned short*)d_out;                  // 16 MiB scratch
  unsigned short* Kb  = Qb + (size_t)8192 * 1024;                // 16 MiB scratch
  unsigned short* Ob  = Xb;   // X dead after QKV projection

  cast_kernel<<<8192, 256, 0, stream>>>(X, Xb, 8388608/4);
  cast4_kernel<<<dim3(1024, 4), 256, 0, stream>>>(Wq, Wk, Wv, Wo,
                                                  Wqb, Wkb, Wvb, Wob, 1048576/4);

  gemm_bt<0><<<1536, 256, 0, stream>>>(Xb, Wqb, Wkb, Wvb, Qb, Kb, Vtb, nullptr);
  attn_kernel<<<512, 512, 0, stream>>>(Qb, Kb, Vtb, Ob);
  gemm_bt<1><<<512, 256, 0, stream>>>(Ob, Wob, nullptr, nullptr,
                                      nullptr, nullptr, nullptr,
                                      (float*)d_out);
}